// Round 1
// baseline (800.197 us; speedup 1.0000x reference)
//
#include <hip/hip_runtime.h>
#include <hip/hip_bf16.h>

#define B_ROWS 16384
#define NODE_F 172
#define MEMD 128
#define NN 1000000

typedef __bf16 bf16;
typedef __bf16 bf16x8 __attribute__((ext_vector_type(8)));
typedef float f32x4 __attribute__((ext_vector_type(4)));

// weight offsets (bf16 elements) inside wb; all stored as [N][Kpad] (B^T, n-major)
#define W_EDGE_O 0        // [128][192]
#define W_MP1_O  24576    // [128][128]
#define W_MP2_O  40960    // [128][128]
#define W_IH_O   57344    // [384][128]
#define W_HH_O   106496   // [384][128]
#define W_NODE_O 155648   // [128][192]
#define W_P1_O   180224   // [128][256]
#define W_P2_O   212992   // [128][128]
#define W_L1_O   229376   // [128][256]
#define W_TOTAL  262144

__device__ __forceinline__ f32x4 mfma16(bf16x8 a, bf16x8 b, f32x4 c) {
    return __builtin_amdgcn_mfma_f32_16x16x32_bf16(a, b, c, 0, 0, 0);
}

__device__ __forceinline__ int clampid(int id) {
    return id < 0 ? 0 : (id > NN - 1 ? NN - 1 : id);
}

__device__ __forceinline__ float sigmoidf_(float x) {
    return 1.f / (1.f + __expf(-x));
}

// One wave: 16 rows x NT n-tiles (16 cols each), K = KSTEPS*32.
// Alds = base of this wave's 16-row block in LDS (row stride lda, bf16).
// Bw = weight base [N][ldb] bf16 (n-major).
template<int NT, int KSTEPS>
__device__ __forceinline__ void gemm_wave(const bf16* Alds, int lda,
                                          const bf16* Bw, int ldb,
                                          f32x4* acc)
{
    int lane = threadIdx.x & 63;
    int p = lane & 15, q = lane >> 4;
    const bf16* ap  = Alds + p * lda + q * 8;
    const bf16* bp0 = Bw + (long)p * ldb + q * 8;
#pragma unroll
    for (int kt = 0; kt < KSTEPS; ++kt) {
        bf16x8 a = *(const bf16x8*)(ap + kt * 32);
#pragma unroll
        for (int j = 0; j < NT; ++j) {
            bf16x8 b = *(const bf16x8*)(bp0 + (long)j * 16 * ldb + kt * 32);
            acc[j] = mfma16(a, b, acc[j]);
        }
    }
}

// ---------------- prep: init last_occ to -1 + convert/transpose weights ----------------
__global__ __launch_bounds__(256) void prep_kernel(
    const float* __restrict__ W_edge, const float* __restrict__ W_mp1,
    const float* __restrict__ W_mp2, const float* __restrict__ W_ih,
    const float* __restrict__ W_hh, const float* __restrict__ W_node,
    const float* __restrict__ W_p1, const float* __restrict__ W_p2,
    const float* __restrict__ W_l1,
    int* __restrict__ last_occ, bf16* __restrict__ wb)
{
    long gid = (long)blockIdx.x * 256 + threadIdx.x;
    if (gid < NN) last_occ[gid] = -1;
    long t = gid;
    if (t < W_TOTAL) {
        float v;
        if (t < W_MP1_O)      { long u = t;            int n = u / 192, k = u % 192; v = (k < NODE_F) ? W_edge[k * 128 + n] : 0.f; }
        else if (t < W_MP2_O) { long u = t - W_MP1_O;  int n = u / 128, k = u % 128; v = W_mp1[k * 128 + n]; }
        else if (t < W_IH_O)  { long u = t - W_MP2_O;  int n = u / 128, k = u % 128; v = W_mp2[k * 128 + n]; }
        else if (t < W_HH_O)  { long u = t - W_IH_O;   v = W_ih[u]; }   // already [384][128] n-major
        else if (t < W_NODE_O){ long u = t - W_HH_O;   v = W_hh[u]; }
        else if (t < W_P1_O)  { long u = t - W_NODE_O; int n = u / 192, k = u % 192; v = (k < NODE_F) ? W_node[k * 128 + n] : 0.f; }
        else if (t < W_P2_O)  { long u = t - W_P1_O;   int n = u / 256, k = u % 256; v = W_p1[k * 128 + n]; }
        else if (t < W_L1_O)  { long u = t - W_P2_O;   int n = u / 128, k = u % 128; v = W_p2[k * 128 + n]; }
        else                  { long u = t - W_L1_O;   int n = u / 256, k = u % 256; v = W_l1[k * 128 + n]; }
        wb[t] = (bf16)v;
    }
}

// ---------------- proc = mp2(relu(mp1(edge@W_edge + b))) ----------------
__global__ __launch_bounds__(256) void proc_kernel(
    const float* __restrict__ edgef, const bf16* __restrict__ wb,
    const float* __restrict__ b_edge, const float* __restrict__ b_mp1,
    const float* __restrict__ b_mp2, bf16* __restrict__ procB)
{
    __shared__ bf16 A0[64 * 200];
    __shared__ bf16 A1[64 * 136];
    __shared__ bf16 A2[64 * 136];
    int tid = threadIdx.x;
    long row0 = (long)blockIdx.x * 64;
    {
        int r0 = tid >> 6, c0 = tid & 63;
        for (int r = r0; r < 64; r += 4)
            for (int c = c0; c < 192; c += 64)
                A0[r * 200 + c] = (c < NODE_F) ? (bf16)edgef[(row0 + r) * NODE_F + c] : (bf16)0.f;
    }
    __syncthreads();
    int w = tid >> 6, lane = tid & 63, p = lane & 15, q = lane >> 4;
    f32x4 acc[8];
    // GEMM1: K=192
    for (int j = 0; j < 8; ++j) acc[j] = (f32x4){0.f, 0.f, 0.f, 0.f};
    gemm_wave<8, 6>(A0 + (w * 16) * 200, 200, wb + W_EDGE_O, 192, acc);
    for (int j = 0; j < 8; ++j) {
        int col = j * 16 + p;
        float bb = b_edge[col];
        for (int v = 0; v < 4; ++v)
            A1[(w * 16 + q * 4 + v) * 136 + col] = (bf16)(acc[j][v] + bb);
    }
    __syncthreads();
    // GEMM2 + relu: K=128
    for (int j = 0; j < 8; ++j) acc[j] = (f32x4){0.f, 0.f, 0.f, 0.f};
    gemm_wave<8, 4>(A1 + (w * 16) * 136, 136, wb + W_MP1_O, 128, acc);
    for (int j = 0; j < 8; ++j) {
        int col = j * 16 + p;
        float bb = b_mp1[col];
        for (int v = 0; v < 4; ++v)
            A2[(w * 16 + q * 4 + v) * 136 + col] = (bf16)fmaxf(acc[j][v] + bb, 0.f);
    }
    __syncthreads();
    // GEMM3: K=128
    for (int j = 0; j < 8; ++j) acc[j] = (f32x4){0.f, 0.f, 0.f, 0.f};
    gemm_wave<8, 4>(A2 + (w * 16) * 136, 136, wb + W_MP2_O, 128, acc);
    for (int j = 0; j < 8; ++j) {
        int col = j * 16 + p;
        float bb = b_mp2[col];
        for (int v = 0; v < 4; ++v)
            procB[(row0 + w * 16 + q * 4 + v) * 128 + col] = (bf16)(acc[j][v] + bb);
    }
}

// ---------------- gather + decay + last-occurrence tag ----------------
__global__ __launch_bounds__(256) void gather_kernel(
    const int* __restrict__ ids, const float* __restrict__ ts,
    const float* __restrict__ memory, const float* __restrict__ last_update,
    int* __restrict__ last_occ, float* __restrict__ cur, int tagbase)
{
    __shared__ float sc_s[32];
    __shared__ int id_s[32];
    int tid = threadIdx.x;
    int rb = blockIdx.x * 32;
    if (tid < 32) {
        int rid = rb + tid;
        int id = clampid(ids[rid]);
        float dtv = fmaxf(ts[rid] - last_update[id], 0.f);
        float sc = __expf(-0.1f * dtv);
        sc_s[tid] = sc; id_s[tid] = id;
        atomicMax(&last_occ[id], tagbase + rid);
    }
    __syncthreads();
    const f32x4* mem4 = (const f32x4*)memory;
    f32x4* cur4 = (f32x4*)cur;
    for (int idx = tid; idx < 32 * 32; idx += 256) {
        int r = idx >> 5, c4 = idx & 31;
        f32x4 v = mem4[(long)id_s[r] * 32 + c4];
        float s = sc_s[r];
        v.x *= s; v.y *= s; v.z *= s; v.w *= s;
        cur4[(long)(rb + r) * 32 + c4] = v;
    }
}

// ---------------- GRU + winner scatter ----------------
__global__ __launch_bounds__(256) void gru_kernel(
    const int* __restrict__ ids, const float* __restrict__ ts,
    const bf16* __restrict__ procB, const float* __restrict__ cur,
    const bf16* __restrict__ wb, const float* __restrict__ b_ih,
    const float* __restrict__ b_hh, const int* __restrict__ last_occ,
    float* __restrict__ memory, float* __restrict__ last_update, int tagbase)
{
    __shared__ bf16 Ap[16 * 136];
    __shared__ bf16 Ac[16 * 136];
    __shared__ float sA[16 * 384];   // gi raw accumulators
    __shared__ float sB[16 * 384];   // gh raw accumulators
    __shared__ int id_s[16];
    __shared__ int win_s[16];
    int tid = threadIdx.x;
    int rb = blockIdx.x * 16;
    if (tid < 16) {
        int rid = rb + tid;
        int id = clampid(ids[rid]);
        id_s[tid] = id;
        int win = (last_occ[id] == tagbase + rid) ? 1 : 0;
        win_s[tid] = win;
        if (win) last_update[id] = ts[rid];
    }
    {   // stage A_proc (bf16 copy) and A_cur (f32 -> bf16)
        int r = tid >> 4, c8 = tid & 15;
        *(bf16x8*)&Ap[r * 136 + c8 * 8] = *(const bf16x8*)&procB[(long)(rb + r) * 128 + c8 * 8];
        f32x4 v0 = *(const f32x4*)&cur[(long)(rb + r) * 128 + c8 * 8];
        f32x4 v1 = *(const f32x4*)&cur[(long)(rb + r) * 128 + c8 * 8 + 4];
        bf16x8 cb;
        cb[0] = (bf16)v0.x; cb[1] = (bf16)v0.y; cb[2] = (bf16)v0.z; cb[3] = (bf16)v0.w;
        cb[4] = (bf16)v1.x; cb[5] = (bf16)v1.y; cb[6] = (bf16)v1.z; cb[7] = (bf16)v1.w;
        *(bf16x8*)&Ac[r * 136 + c8 * 8] = cb;
    }
    __syncthreads();
    int w = tid >> 6, lane = tid & 63, p = lane & 15, q = lane >> 4;
    // 48 column-tiles: 24 for gi (A=Ap, W_ih), 24 for gh (A=Ac, W_hh); 12 per wave
#pragma unroll
    for (int j = 0; j < 12; ++j) {
        int cidx = w * 12 + j;
        bool is_gi = cidx < 24;
        int nt = is_gi ? cidx : cidx - 24;
        const bf16* Al = (is_gi ? Ap : Ac) + p * 136 + q * 8;
        const bf16* Bw = wb + (is_gi ? W_IH_O : W_HH_O) + (long)(nt * 16 + p) * 128 + q * 8;
        f32x4 acc = (f32x4){0.f, 0.f, 0.f, 0.f};
#pragma unroll
        for (int kt = 0; kt < 4; ++kt) {
            bf16x8 a = *(const bf16x8*)(Al + kt * 32);
            bf16x8 b = *(const bf16x8*)(Bw + kt * 32);
            acc = mfma16(a, b, acc);
        }
        float* S = is_gi ? sA : sB;
        int col = nt * 16 + p;
        for (int v = 0; v < 4; ++v) S[(q * 4 + v) * 384 + col] = acc[v];
    }
    __syncthreads();
    // elementwise GRU + winner scatter
    for (int idx = tid; idx < 16 * 128; idx += 256) {
        int r = idx >> 7, c = idx & 127;
        float ir = sA[r * 384 + c]       + b_ih[c];
        float iz = sA[r * 384 + 128 + c] + b_ih[128 + c];
        float in_ = sA[r * 384 + 256 + c] + b_ih[256 + c];
        float hr = sB[r * 384 + c]       + b_hh[c];
        float hz = sB[r * 384 + 128 + c] + b_hh[128 + c];
        float hn = sB[r * 384 + 256 + c] + b_hh[256 + c];
        float rg = sigmoidf_(ir + hr);
        float zg = sigmoidf_(iz + hz);
        float ng = tanhf(in_ + rg * hn);
        float h = cur[(long)(rb + r) * 128 + c];
        float nv = (1.f - zg) * ng + zg * h;
        if (win_s[r]) memory[(long)id_s[r] * 128 + c] = nv;
    }
}

// ---------------- embeddings (both sides via blockIdx.y) ----------------
__global__ __launch_bounds__(256) void emb_kernel(
    const int* __restrict__ src_ids, const int* __restrict__ dst_ids,
    const float* __restrict__ src_feat, const float* __restrict__ dst_feat,
    const float* __restrict__ ts, const float* __restrict__ memory,
    const float* __restrict__ last_update, const bf16* __restrict__ wb,
    const float* __restrict__ b_node, const float* __restrict__ b_p1,
    const float* __restrict__ b_p2, bf16* __restrict__ embS,
    bf16* __restrict__ embD, float* __restrict__ dout)
{
    int side = blockIdx.y;
    const int* ids = side ? dst_ids : src_ids;
    const float* feats = side ? dst_feat : src_feat;
    bf16* embOut = side ? embD : embS;
    __shared__ bf16 A0[64 * 200];
    __shared__ bf16 Comb[64 * 264];   // cols 0..127 attended, 128..255 node_emb
    __shared__ bf16 A2[64 * 136];
    __shared__ float sc_s[64];
    __shared__ int id_s[64];
    int tid = threadIdx.x;
    long row0 = (long)blockIdx.x * 64;
    if (tid < 64) {
        int rid = (int)row0 + tid;
        int id = clampid(ids[rid]);
        float dtv = fmaxf(ts[rid] - last_update[id], 0.f);
        float sc = __expf(-0.1f * dtv);
        sc_s[tid] = sc; id_s[tid] = id;
        dout[B_ROWS + side * B_ROWS + rid] = sc;   // score output
    }
    {
        int r0 = tid >> 6, c0 = tid & 63;
        for (int r = r0; r < 64; r += 4)
            for (int c = c0; c < 192; c += 64)
                A0[r * 200 + c] = (c < NODE_F) ? (bf16)feats[(row0 + r) * NODE_F + c] : (bf16)0.f;
    }
    __syncthreads();
    {   // attended = memory[id] * score^2 -> Comb cols 0..127
        const f32x4* mem4 = (const f32x4*)memory;
        for (int idx = tid; idx < 64 * 32; idx += 256) {
            int r = idx >> 5, c4 = idx & 31;
            float s = sc_s[r]; s = s * s;
            f32x4 v = mem4[(long)id_s[r] * 32 + c4];
            int base = r * 264 + c4 * 4;
            Comb[base + 0] = (bf16)(v.x * s);
            Comb[base + 1] = (bf16)(v.y * s);
            Comb[base + 2] = (bf16)(v.z * s);
            Comb[base + 3] = (bf16)(v.w * s);
        }
    }
    __syncthreads();
    int w = tid >> 6, lane = tid & 63, p = lane & 15, q = lane >> 4;
    f32x4 acc[8];
    // node_emb GEMM: K=192 -> Comb cols 128..255
    for (int j = 0; j < 8; ++j) acc[j] = (f32x4){0.f, 0.f, 0.f, 0.f};
    gemm_wave<8, 6>(A0 + (w * 16) * 200, 200, wb + W_NODE_O, 192, acc);
    for (int j = 0; j < 8; ++j) {
        int col = j * 16 + p;
        float bb = b_node[col];
        for (int v = 0; v < 4; ++v)
            Comb[(w * 16 + q * 4 + v) * 264 + 128 + col] = (bf16)(acc[j][v] + bb);
    }
    __syncthreads();
    // p1 GEMM: K=256, relu
    for (int j = 0; j < 8; ++j) acc[j] = (f32x4){0.f, 0.f, 0.f, 0.f};
    gemm_wave<8, 8>(Comb + (w * 16) * 264, 264, wb + W_P1_O, 256, acc);
    for (int j = 0; j < 8; ++j) {
        int col = j * 16 + p;
        float bb = b_p1[col];
        for (int v = 0; v < 4; ++v)
            A2[(w * 16 + q * 4 + v) * 136 + col] = (bf16)fmaxf(acc[j][v] + bb, 0.f);
    }
    __syncthreads();
    // p2 GEMM: K=128
    for (int j = 0; j < 8; ++j) acc[j] = (f32x4){0.f, 0.f, 0.f, 0.f};
    gemm_wave<8, 4>(A2 + (w * 16) * 136, 136, wb + W_P2_O, 128, acc);
    for (int j = 0; j < 8; ++j) {
        int col = j * 16 + p;
        float bb = b_p2[col];
        for (int v = 0; v < 4; ++v)
            embOut[(row0 + w * 16 + q * 4 + v) * 128 + col] = (bf16)(acc[j][v] + bb);
    }
}

// ---------------- link predictor ----------------
__global__ __launch_bounds__(256) void link_kernel(
    const bf16* __restrict__ embS, const bf16* __restrict__ embD,
    const bf16* __restrict__ wb, const float* __restrict__ b_l1,
    const float* __restrict__ W_l2, const float* __restrict__ b_l2,
    float* __restrict__ out)
{
    __shared__ bf16 A[64 * 264];
    __shared__ float H[64 * 132];
    int tid = threadIdx.x;
    long row0 = (long)blockIdx.x * 64;
    for (int g = tid; g < 64 * 32; g += 256) {
        int r = g >> 5, c8 = g & 31;
        const bf16* src = (c8 < 16) ? &embS[(row0 + r) * 128 + c8 * 8]
                                    : &embD[(row0 + r) * 128 + (c8 - 16) * 8];
        *(bf16x8*)&A[r * 264 + c8 * 8] = *(const bf16x8*)src;
    }
    __syncthreads();
    int w = tid >> 6, lane = tid & 63, p = lane & 15, q = lane >> 4;
    f32x4 acc[8];
    for (int j = 0; j < 8; ++j) acc[j] = (f32x4){0.f, 0.f, 0.f, 0.f};
    gemm_wave<8, 8>(A + (w * 16) * 264, 264, wb + W_L1_O, 256, acc);
    for (int j = 0; j < 8; ++j) {
        int col = j * 16 + p;
        float bb = b_l1[col];
        for (int v = 0; v < 4; ++v)
            H[(w * 16 + q * 4 + v) * 132 + col] = fmaxf(acc[j][v] + bb, 0.f);
    }
    __syncthreads();
    if (tid < 64) {
        float a = b_l2[0];
        for (int c = 0; c < 128; ++c) a += H[tid * 132 + c] * W_l2[c];
        out[row0 + tid] = sigmoidf_(a);
    }
}

extern "C" void kernel_launch(void* const* d_in, const int* in_sizes, int n_in,
                              void* d_out, int out_size, void* d_ws, size_t ws_size,
                              hipStream_t stream)
{
    const int*   src_ids  = (const int*)d_in[0];
    const int*   dst_ids  = (const int*)d_in[1];
    const float* src_feat = (const float*)d_in[2];
    const float* dst_feat = (const float*)d_in[3];
    const float* ts       = (const float*)d_in[4];
    const float* edgef    = (const float*)d_in[5];
    float* memory         = (float*)d_in[6];     // mutated in place; harness restores
    float* last_update    = (float*)d_in[7];     // mutated in place; harness restores
    const float* W_edge = (const float*)d_in[8],  *b_edge = (const float*)d_in[9];
    const float* W_mp1  = (const float*)d_in[10], *b_mp1  = (const float*)d_in[11];
    const float* W_mp2  = (const float*)d_in[12], *b_mp2  = (const float*)d_in[13];
    const float* W_ih   = (const float*)d_in[14], *W_hh   = (const float*)d_in[15];
    const float* b_ih   = (const float*)d_in[16], *b_hh   = (const float*)d_in[17];
    const float* W_node = (const float*)d_in[18], *b_node = (const float*)d_in[19];
    const float* W_p1   = (const float*)d_in[20], *b_p1   = (const float*)d_in[21];
    const float* W_p2   = (const float*)d_in[22], *b_p2   = (const float*)d_in[23];
    const float* W_l1   = (const float*)d_in[24], *b_l1   = (const float*)d_in[25];
    const float* W_l2   = (const float*)d_in[26], *b_l2   = (const float*)d_in[27];

    char* ws = (char*)d_ws;
    int*   last_occ = (int*)ws;                         // 4,000,000 B
    bf16*  wb       = (bf16*)(ws + 4000000);            // 524,288 B
    bf16*  procB    = (bf16*)(ws + 4524288);            // 4 MiB
    float* cur      = (float*)(ws + 8718592);           // 8 MiB
    bf16*  embS     = (bf16*)(ws + 17107200);           // 4 MiB
    bf16*  embD     = (bf16*)(ws + 21301504);           // 4 MiB
    float* dout     = (float*)d_out;

    prep_kernel<<<3907, 256, 0, stream>>>(W_edge, W_mp1, W_mp2, W_ih, W_hh,
                                          W_node, W_p1, W_p2, W_l1, last_occ, wb);
    proc_kernel<<<256, 256, 0, stream>>>(edgef, wb, b_edge, b_mp1, b_mp2, procB);
    // src round
    gather_kernel<<<512, 256, 0, stream>>>(src_ids, ts, memory, last_update,
                                           last_occ, cur, 0);
    gru_kernel<<<1024, 256, 0, stream>>>(src_ids, ts, procB, cur, wb, b_ih, b_hh,
                                         last_occ, memory, last_update, 0);
    // dst round
    gather_kernel<<<512, 256, 0, stream>>>(dst_ids, ts, memory, last_update,
                                           last_occ, cur, B_ROWS);
    gru_kernel<<<1024, 256, 0, stream>>>(dst_ids, ts, procB, cur, wb, b_ih, b_hh,
                                         last_occ, memory, last_update, B_ROWS);
    // embeddings (side 0 = src, side 1 = dst)
    emb_kernel<<<dim3(256, 2), 256, 0, stream>>>(src_ids, dst_ids, src_feat, dst_feat,
                                                 ts, memory, last_update, wb,
                                                 b_node, b_p1, b_p2, embS, embD, dout);
    link_kernel<<<256, 256, 0, stream>>>(embS, embD, wb, b_l1, W_l2, b_l2, dout);
}

// Round 2
// 779.851 us; speedup vs baseline: 1.0261x; 1.0261x over previous
//
#include <hip/hip_runtime.h>
#include <hip/hip_bf16.h>

#define B_ROWS 16384
#define NODE_F 172
#define MEMD 128
#define NN 1000000

typedef __bf16 bf16;
typedef __bf16 bf16x8 __attribute__((ext_vector_type(8)));
typedef float f32x4 __attribute__((ext_vector_type(4)));

// weight offsets (bf16 elements) inside wb; all stored as [N][Kpad] (B^T, n-major)
#define W_EDGE_O 0        // [128][192]
#define W_MP1_O  24576    // [128][128]
#define W_MP2_O  40960    // [128][128]
#define W_IH_O   57344    // [384][128]
#define W_HH_O   106496   // [384][128]
#define W_NODE_O 155648   // [128][192]
#define W_P1_O   180224   // [128][256]
#define W_P2_O   212992   // [128][128]
#define W_L1_O   229376   // [128][256]
#define W_TOTAL  262144

__device__ __forceinline__ f32x4 mfma16(bf16x8 a, bf16x8 b, f32x4 c) {
    return __builtin_amdgcn_mfma_f32_16x16x32_bf16(a, b, c, 0, 0, 0);
}

__device__ __forceinline__ int clampid(int id) {
    return id < 0 ? 0 : (id > NN - 1 ? NN - 1 : id);
}

__device__ __forceinline__ float sigmoidf_(float x) {
    return 1.f / (1.f + __expf(-x));
}

__device__ __forceinline__ float tanhf_(float x) {
    // tanh(x) = 1 - 2/(exp(2x)+1); exact limits at +-inf, fine for 2e-2 tol
    return 1.f - 2.f / (__expf(2.f * x) + 1.f);
}

// One wave: 16 rows x NT n-tiles (16 cols each), K = KSTEPS*32.
template<int NT, int KSTEPS>
__device__ __forceinline__ void gemm_wave(const bf16* Alds, int lda,
                                          const bf16* Bw, int ldb,
                                          f32x4* acc)
{
    int lane = threadIdx.x & 63;
    int p = lane & 15, q = lane >> 4;
    const bf16* ap  = Alds + p * lda + q * 8;
    const bf16* bp0 = Bw + (long)p * ldb + q * 8;
#pragma unroll
    for (int kt = 0; kt < KSTEPS; ++kt) {
        bf16x8 a = *(const bf16x8*)(ap + kt * 32);
#pragma unroll
        for (int j = 0; j < NT; ++j) {
            bf16x8 b = *(const bf16x8*)(bp0 + (long)j * 16 * ldb + kt * 32);
            acc[j] = mfma16(a, b, acc[j]);
        }
    }
}

// ---------------- prep: init occS/occD to -1 (int4 stores) + weight cast/transpose ----------------
__global__ __launch_bounds__(256) void prep_kernel(
    const float* __restrict__ W_edge, const float* __restrict__ W_mp1,
    const float* __restrict__ W_mp2, const float* __restrict__ W_ih,
    const float* __restrict__ W_hh, const float* __restrict__ W_node,
    const float* __restrict__ W_p1, const float* __restrict__ W_p2,
    const float* __restrict__ W_l1,
    int* __restrict__ occS, int* __restrict__ occD, bf16* __restrict__ wb)
{
    int gid = blockIdx.x * 256 + threadIdx.x;
    if (gid < NN / 4) {
        int4 m1 = {-1, -1, -1, -1};
        ((int4*)occS)[gid] = m1;
        ((int4*)occD)[gid] = m1;
    }
    int t = gid;
    if (t < W_TOTAL) {
        float v;
        if (t < W_MP1_O)      { int u = t;            int n = u / 192, k = u % 192; v = (k < NODE_F) ? W_edge[k * 128 + n] : 0.f; }
        else if (t < W_MP2_O) { int u = t - W_MP1_O;  int n = u / 128, k = u % 128; v = W_mp1[k * 128 + n]; }
        else if (t < W_IH_O)  { int u = t - W_MP2_O;  int n = u / 128, k = u % 128; v = W_mp2[k * 128 + n]; }
        else if (t < W_HH_O)  { int u = t - W_IH_O;   v = W_ih[u]; }   // already [384][128] n-major
        else if (t < W_NODE_O){ int u = t - W_HH_O;   v = W_hh[u]; }
        else if (t < W_P1_O)  { int u = t - W_NODE_O; int n = u / 192, k = u % 192; v = (k < NODE_F) ? W_node[k * 128 + n] : 0.f; }
        else if (t < W_P2_O)  { int u = t - W_P1_O;   int n = u / 256, k = u % 256; v = W_p1[k * 128 + n]; }
        else if (t < W_L1_O)  { int u = t - W_P2_O;   int n = u / 128, k = u % 128; v = W_p2[k * 128 + n]; }
        else                  { int u = t - W_L1_O;   int n = u / 256, k = u % 256; v = W_l1[k * 128 + n]; }
        wb[t] = (bf16)v;
    }
}

// ---------------- proc = mp2(relu(mp1(edge@W_edge + b))) + last-occurrence tagging ----------------
__global__ __launch_bounds__(256) void proc_kernel(
    const float* __restrict__ edgef, const bf16* __restrict__ wb,
    const float* __restrict__ b_edge, const float* __restrict__ b_mp1,
    const float* __restrict__ b_mp2, const int* __restrict__ src_ids,
    const int* __restrict__ dst_ids, int* __restrict__ occS,
    int* __restrict__ occD, bf16* __restrict__ procB)
{
    __shared__ bf16 A0[64 * 200];
    __shared__ bf16 A1[64 * 136];
    __shared__ bf16 A2[64 * 136];
    int tid = threadIdx.x;
    long row0 = (long)blockIdx.x * 64;
    if (tid < 64) {   // last-occurrence tags for both rounds (occ tables inited in prep)
        int rid = (int)row0 + tid;
        atomicMax(&occS[clampid(src_ids[rid])], rid);
        atomicMax(&occD[clampid(dst_ids[rid])], rid);
    }
    {
        int r0 = tid >> 6, c0 = tid & 63;
        for (int r = r0; r < 64; r += 4)
            for (int c = c0; c < 192; c += 64)
                A0[r * 200 + c] = (c < NODE_F) ? (bf16)edgef[(row0 + r) * NODE_F + c] : (bf16)0.f;
    }
    __syncthreads();
    int w = tid >> 6, lane = tid & 63, p = lane & 15, q = lane >> 4;
    f32x4 acc[8];
    // GEMM1: K=192
    for (int j = 0; j < 8; ++j) acc[j] = (f32x4){0.f, 0.f, 0.f, 0.f};
    gemm_wave<8, 6>(A0 + (w * 16) * 200, 200, wb + W_EDGE_O, 192, acc);
    for (int j = 0; j < 8; ++j) {
        int col = j * 16 + p;
        float bb = b_edge[col];
        for (int v = 0; v < 4; ++v)
            A1[(w * 16 + q * 4 + v) * 136 + col] = (bf16)(acc[j][v] + bb);
    }
    __syncthreads();
    // GEMM2 + relu: K=128
    for (int j = 0; j < 8; ++j) acc[j] = (f32x4){0.f, 0.f, 0.f, 0.f};
    gemm_wave<8, 4>(A1 + (w * 16) * 136, 136, wb + W_MP1_O, 128, acc);
    for (int j = 0; j < 8; ++j) {
        int col = j * 16 + p;
        float bb = b_mp1[col];
        for (int v = 0; v < 4; ++v)
            A2[(w * 16 + q * 4 + v) * 136 + col] = (bf16)fmaxf(acc[j][v] + bb, 0.f);
    }
    __syncthreads();
    // GEMM3: K=128
    for (int j = 0; j < 8; ++j) acc[j] = (f32x4){0.f, 0.f, 0.f, 0.f};
    gemm_wave<8, 4>(A2 + (w * 16) * 136, 136, wb + W_MP2_O, 128, acc);
    for (int j = 0; j < 8; ++j) {
        int col = j * 16 + p;
        float bb = b_mp2[col];
        for (int v = 0; v < 4; ++v)
            procB[(row0 + w * 16 + q * 4 + v) * 128 + col] = (bf16)(acc[j][v] + bb);
    }
}

// ---------------- fused gather + decay + GRU; writes every row to newmemOut[rid] ----------------
// round==0: gather from memory/last_update. round==1: indirect through occPrev/newmemPrev.
__global__ __launch_bounds__(256) void gru_kernel(
    const int* __restrict__ ids, const float* __restrict__ ts,
    const bf16* __restrict__ procB, const float* __restrict__ memory,
    const float* __restrict__ last_update, const int* __restrict__ occPrev,
    const float* __restrict__ newmemPrev, const bf16* __restrict__ wb,
    const float* __restrict__ b_ih, const float* __restrict__ b_hh,
    float* __restrict__ newmemOut, int round)
{
    __shared__ bf16 Ap[16 * 136];
    __shared__ bf16 Ac[16 * 136];
    __shared__ float curF[16 * 128];
    __shared__ float sA[16 * 384];   // gi raw accumulators
    __shared__ float sB[16 * 384];   // gh raw accumulators
    __shared__ float sc_s[16];
    __shared__ const float* rowp_s[16];
    int tid = threadIdx.x;
    int rb = blockIdx.x * 16;
    if (tid < 16) {
        int rid = rb + tid;
        int id = clampid(ids[rid]);
        const float* rowp = &memory[(long)id * MEMD];
        float lu = last_update[id];
        if (round) {
            int tg = occPrev[id];
            if (tg >= 0) { rowp = &newmemPrev[(long)tg * MEMD]; lu = ts[tg]; }
        }
        float dtv = fmaxf(ts[rid] - lu, 0.f);
        sc_s[tid] = __expf(-0.1f * dtv);
        rowp_s[tid] = rowp;
    }
    __syncthreads();
    {   // stage A_proc (bf16 copy) and cur (gather + decay; f32 in LDS + bf16 in Ac)
        int r = tid >> 4, c8 = tid & 15;
        *(bf16x8*)&Ap[r * 136 + c8 * 8] = *(const bf16x8*)&procB[(long)(rb + r) * 128 + c8 * 8];
        float s = sc_s[r];
        f32x4 v0 = *(const f32x4*)(rowp_s[r] + c8 * 8);
        f32x4 v1 = *(const f32x4*)(rowp_s[r] + c8 * 8 + 4);
        v0.x *= s; v0.y *= s; v0.z *= s; v0.w *= s;
        v1.x *= s; v1.y *= s; v1.z *= s; v1.w *= s;
        *(f32x4*)&curF[r * 128 + c8 * 8] = v0;
        *(f32x4*)&curF[r * 128 + c8 * 8 + 4] = v1;
        bf16x8 cb;
        cb[0] = (bf16)v0.x; cb[1] = (bf16)v0.y; cb[2] = (bf16)v0.z; cb[3] = (bf16)v0.w;
        cb[4] = (bf16)v1.x; cb[5] = (bf16)v1.y; cb[6] = (bf16)v1.z; cb[7] = (bf16)v1.w;
        *(bf16x8*)&Ac[r * 136 + c8 * 8] = cb;
    }
    __syncthreads();
    int w = tid >> 6, lane = tid & 63, p = lane & 15, q = lane >> 4;
    // 48 column-tiles: 24 for gi (A=Ap, W_ih), 24 for gh (A=Ac, W_hh); 12 per wave
#pragma unroll
    for (int j = 0; j < 12; ++j) {
        int cidx = w * 12 + j;
        bool is_gi = cidx < 24;
        int nt = is_gi ? cidx : cidx - 24;
        const bf16* Al = (is_gi ? Ap : Ac) + p * 136 + q * 8;
        const bf16* Bw = wb + (is_gi ? W_IH_O : W_HH_O) + (long)(nt * 16 + p) * 128 + q * 8;
        f32x4 acc = (f32x4){0.f, 0.f, 0.f, 0.f};
#pragma unroll
        for (int kt = 0; kt < 4; ++kt) {
            bf16x8 a = *(const bf16x8*)(Al + kt * 32);
            bf16x8 b = *(const bf16x8*)(Bw + kt * 32);
            acc = mfma16(a, b, acc);
        }
        float* S = is_gi ? sA : sB;
        int col = nt * 16 + p;
        for (int v = 0; v < 4; ++v) S[(q * 4 + v) * 384 + col] = acc[v];
    }
    __syncthreads();
    // elementwise GRU -> newmemOut[rid] (all rows; winner resolved at read time)
    for (int idx = tid; idx < 16 * 128; idx += 256) {
        int r = idx >> 7, c = idx & 127;
        float ir = sA[r * 384 + c]        + b_ih[c];
        float iz = sA[r * 384 + 128 + c]  + b_ih[128 + c];
        float in_ = sA[r * 384 + 256 + c] + b_ih[256 + c];
        float hr = sB[r * 384 + c]        + b_hh[c];
        float hz = sB[r * 384 + 128 + c]  + b_hh[128 + c];
        float hn = sB[r * 384 + 256 + c]  + b_hh[256 + c];
        float rg = sigmoidf_(ir + hr);
        float zg = sigmoidf_(iz + hz);
        float ng = tanhf_(in_ + rg * hn);
        float h = curF[r * 128 + c];
        newmemOut[(long)(rb + r) * 128 + c] = (1.f - zg) * ng + zg * h;
    }
}

// ---------------- embeddings (both sides via blockIdx.y) ----------------
__global__ __launch_bounds__(256) void emb_kernel(
    const int* __restrict__ src_ids, const int* __restrict__ dst_ids,
    const float* __restrict__ src_feat, const float* __restrict__ dst_feat,
    const float* __restrict__ ts, const float* __restrict__ memory,
    const float* __restrict__ last_update, const int* __restrict__ occS,
    const int* __restrict__ occD, const float* __restrict__ newmemS,
    const float* __restrict__ newmemD, const bf16* __restrict__ wb,
    const float* __restrict__ b_node, const float* __restrict__ b_p1,
    const float* __restrict__ b_p2, bf16* __restrict__ embS,
    bf16* __restrict__ embD, float* __restrict__ dout)
{
    int side = blockIdx.y;
    const int* ids = side ? dst_ids : src_ids;
    const float* feats = side ? dst_feat : src_feat;
    bf16* embOut = side ? embD : embS;
    __shared__ bf16 A0[64 * 200];
    __shared__ bf16 Comb[64 * 264];   // cols 0..127 attended, 128..255 node_emb
    __shared__ bf16 A2[64 * 136];
    __shared__ float sc_s[64];
    __shared__ const float* rowp_s[64];
    int tid = threadIdx.x;
    long row0 = (long)blockIdx.x * 64;
    if (tid < 64) {
        int rid = (int)row0 + tid;
        int id = clampid(ids[rid]);
        const float* rowp = &memory[(long)id * MEMD];
        float lu = last_update[id];
        int tgD = occD[id], tgS = occS[id];
        if (tgD >= 0)      { rowp = &newmemD[(long)tgD * MEMD]; lu = ts[tgD]; }
        else if (tgS >= 0) { rowp = &newmemS[(long)tgS * MEMD]; lu = ts[tgS]; }
        float dtv = fmaxf(ts[rid] - lu, 0.f);
        float sc = __expf(-0.1f * dtv);
        sc_s[tid] = sc; rowp_s[tid] = rowp;
        dout[B_ROWS + side * B_ROWS + rid] = sc;   // score output
    }
    {
        int r0 = tid >> 6, c0 = tid & 63;
        for (int r = r0; r < 64; r += 4)
            for (int c = c0; c < 192; c += 64)
                A0[r * 200 + c] = (c < NODE_F) ? (bf16)feats[(row0 + r) * NODE_F + c] : (bf16)0.f;
    }
    __syncthreads();
    {   // attended = mem_row * score^2 -> Comb cols 0..127
        for (int idx = tid; idx < 64 * 16; idx += 256) {
            int r = idx >> 4, c8 = idx & 15;
            float s = sc_s[r]; s = s * s;
            f32x4 v0 = *(const f32x4*)(rowp_s[r] + c8 * 8);
            f32x4 v1 = *(const f32x4*)(rowp_s[r] + c8 * 8 + 4);
            bf16x8 cb;
            cb[0] = (bf16)(v0.x * s); cb[1] = (bf16)(v0.y * s);
            cb[2] = (bf16)(v0.z * s); cb[3] = (bf16)(v0.w * s);
            cb[4] = (bf16)(v1.x * s); cb[5] = (bf16)(v1.y * s);
            cb[6] = (bf16)(v1.z * s); cb[7] = (bf16)(v1.w * s);
            *(bf16x8*)&Comb[r * 264 + c8 * 8] = cb;
        }
    }
    __syncthreads();
    int w = tid >> 6, lane = tid & 63, p = lane & 15, q = lane >> 4;
    f32x4 acc[8];
    // node_emb GEMM: K=192 -> Comb cols 128..255
    for (int j = 0; j < 8; ++j) acc[j] = (f32x4){0.f, 0.f, 0.f, 0.f};
    gemm_wave<8, 6>(A0 + (w * 16) * 200, 200, wb + W_NODE_O, 192, acc);
    for (int j = 0; j < 8; ++j) {
        int col = j * 16 + p;
        float bb = b_node[col];
        for (int v = 0; v < 4; ++v)
            Comb[(w * 16 + q * 4 + v) * 264 + 128 + col] = (bf16)(acc[j][v] + bb);
    }
    __syncthreads();
    // p1 GEMM: K=256, relu
    for (int j = 0; j < 8; ++j) acc[j] = (f32x4){0.f, 0.f, 0.f, 0.f};
    gemm_wave<8, 8>(Comb + (w * 16) * 264, 264, wb + W_P1_O, 256, acc);
    for (int j = 0; j < 8; ++j) {
        int col = j * 16 + p;
        float bb = b_p1[col];
        for (int v = 0; v < 4; ++v)
            A2[(w * 16 + q * 4 + v) * 136 + col] = (bf16)fmaxf(acc[j][v] + bb, 0.f);
    }
    __syncthreads();
    // p2 GEMM: K=128
    for (int j = 0; j < 8; ++j) acc[j] = (f32x4){0.f, 0.f, 0.f, 0.f};
    gemm_wave<8, 4>(A2 + (w * 16) * 136, 136, wb + W_P2_O, 128, acc);
    for (int j = 0; j < 8; ++j) {
        int col = j * 16 + p;
        float bb = b_p2[col];
        for (int v = 0; v < 4; ++v)
            embOut[(row0 + w * 16 + q * 4 + v) * 128 + col] = (bf16)(acc[j][v] + bb);
    }
}

// ---------------- link predictor ----------------
__global__ __launch_bounds__(256) void link_kernel(
    const bf16* __restrict__ embS, const bf16* __restrict__ embD,
    const bf16* __restrict__ wb, const float* __restrict__ b_l1,
    const float* __restrict__ W_l2, const float* __restrict__ b_l2,
    float* __restrict__ out)
{
    __shared__ bf16 A[64 * 264];
    __shared__ float H[64 * 132];
    int tid = threadIdx.x;
    long row0 = (long)blockIdx.x * 64;
    for (int g = tid; g < 64 * 32; g += 256) {
        int r = g >> 5, c8 = g & 31;
        const bf16* src = (c8 < 16) ? &embS[(row0 + r) * 128 + c8 * 8]
                                    : &embD[(row0 + r) * 128 + (c8 - 16) * 8];
        *(bf16x8*)&A[r * 264 + c8 * 8] = *(const bf16x8*)src;
    }
    __syncthreads();
    int w = tid >> 6, lane = tid & 63, p = lane & 15, q = lane >> 4;
    f32x4 acc[8];
    for (int j = 0; j < 8; ++j) acc[j] = (f32x4){0.f, 0.f, 0.f, 0.f};
    gemm_wave<8, 8>(A + (w * 16) * 264, 264, wb + W_L1_O, 256, acc);
    for (int j = 0; j < 8; ++j) {
        int col = j * 16 + p;
        float bb = b_l1[col];
        for (int v = 0; v < 4; ++v)
            H[(w * 16 + q * 4 + v) * 132 + col] = fmaxf(acc[j][v] + bb, 0.f);
    }
    __syncthreads();
    if (tid < 64) {
        float a = b_l2[0];
        for (int c = 0; c < 128; ++c) a += H[tid * 132 + c] * W_l2[c];
        out[row0 + tid] = sigmoidf_(a);
    }
}

extern "C" void kernel_launch(void* const* d_in, const int* in_sizes, int n_in,
                              void* d_out, int out_size, void* d_ws, size_t ws_size,
                              hipStream_t stream)
{
    const int*   src_ids  = (const int*)d_in[0];
    const int*   dst_ids  = (const int*)d_in[1];
    const float* src_feat = (const float*)d_in[2];
    const float* dst_feat = (const float*)d_in[3];
    const float* ts       = (const float*)d_in[4];
    const float* edgef    = (const float*)d_in[5];
    const float* memory   = (const float*)d_in[6];     // read-only now (COW)
    const float* last_update = (const float*)d_in[7];  // read-only now
    const float* W_edge = (const float*)d_in[8],  *b_edge = (const float*)d_in[9];
    const float* W_mp1  = (const float*)d_in[10], *b_mp1  = (const float*)d_in[11];
    const float* W_mp2  = (const float*)d_in[12], *b_mp2  = (const float*)d_in[13];
    const float* W_ih   = (const float*)d_in[14], *W_hh   = (const float*)d_in[15];
    const float* b_ih   = (const float*)d_in[16], *b_hh   = (const float*)d_in[17];
    const float* W_node = (const float*)d_in[18], *b_node = (const float*)d_in[19];
    const float* W_p1   = (const float*)d_in[20], *b_p1   = (const float*)d_in[21];
    const float* W_p2   = (const float*)d_in[22], *b_p2   = (const float*)d_in[23];
    const float* W_l1   = (const float*)d_in[24], *b_l1   = (const float*)d_in[25];
    const float* W_l2   = (const float*)d_in[26], *b_l2   = (const float*)d_in[27];

    char* ws = (char*)d_ws;
    int*   occS     = (int*)ws;                        // 4,000,000 B
    int*   occD     = (int*)(ws + 4000000);            // 4,000,000 B
    bf16*  wb       = (bf16*)(ws + 8000000);           // 524,288 B
    bf16*  procB    = (bf16*)(ws + 8524288);           // 4 MiB
    float* newmemS  = (float*)(ws + 12718592);         // 8 MiB
    float* newmemD  = (float*)(ws + 21107200);         // 8 MiB
    bf16*  embS     = (bf16*)(ws + 29495808);          // 4 MiB
    bf16*  embD     = (bf16*)(ws + 33690112);          // 4 MiB
    float* dout     = (float*)d_out;

    prep_kernel<<<1024, 256, 0, stream>>>(W_edge, W_mp1, W_mp2, W_ih, W_hh,
                                          W_node, W_p1, W_p2, W_l1, occS, occD, wb);
    proc_kernel<<<256, 256, 0, stream>>>(edgef, wb, b_edge, b_mp1, b_mp2,
                                         src_ids, dst_ids, occS, occD, procB);
    // round 0 (src): gather from pristine memory
    gru_kernel<<<1024, 256, 0, stream>>>(src_ids, ts, procB, memory, last_update,
                                         occS, newmemS, wb, b_ih, b_hh, newmemS, 0);
    // round 1 (dst): gather through occS/newmemS indirection
    gru_kernel<<<1024, 256, 0, stream>>>(dst_ids, ts, procB, memory, last_update,
                                         occS, newmemS, wb, b_ih, b_hh, newmemD, 1);
    // embeddings (side 0 = src, side 1 = dst), read through occD -> occS -> memory
    emb_kernel<<<dim3(256, 2), 256, 0, stream>>>(src_ids, dst_ids, src_feat, dst_feat,
                                                 ts, memory, last_update, occS, occD,
                                                 newmemS, newmemD, wb,
                                                 b_node, b_p1, b_p2, embS, embD, dout);
    link_kernel<<<256, 256, 0, stream>>>(embS, embD, wb, b_l1, W_l2, b_l2, dout);
}